// Round 2
// baseline (301.964 us; speedup 1.0000x reference)
//
#include <hip/hip_runtime.h>

// out[b,d] = sum_{j=0..x-1} hidden[b, start+j, d]
// start = clamp(sum(mask[B-1,:]) - x, 0, S-x)   (lax.dynamic_slice clamping)
//
// Two-stage, no atomics, no output memset:
//  k1: grid (B, JSPLIT). Block (b,jc) sums its 8-j chunk of row b into
//      ws[jc][b][d] (float4). Mask-row sum recomputed per block (8 KB, L2-hot).
//  k2: out[g] = sum_jc ws[jc][g]  (1 MB L2-hot read, 128 KB write).

#define JSPLIT 8

__global__ __launch_bounds__(256) void srs_partial(
    const float4* __restrict__ hidden,
    const int* __restrict__ mask,
    const int* __restrict__ xp,
    float4* __restrict__ ws,
    int B, int S, int D4)
{
    __shared__ int s_wave[4];
    __shared__ int s_start;
    const int tid = threadIdx.x;
    const int x = *xp;

    // mask-row (B-1) sum -> start
    int acc = 0;
    const int* mrow = mask + (size_t)(B - 1) * S;
    for (int i = tid; i < S; i += 256) acc += mrow[i];
    #pragma unroll
    for (int off = 32; off > 0; off >>= 1) acc += __shfl_down(acc, off, 64);
    if ((tid & 63) == 0) s_wave[tid >> 6] = acc;
    __syncthreads();
    if (tid == 0) {
        int start = (s_wave[0] + s_wave[1] + s_wave[2] + s_wave[3]) - x;
        if (start < 0) start = 0;
        if (start > S - x) start = S - x;
        s_start = start;
    }
    __syncthreads();
    const int start = s_start;

    const int b  = blockIdx.x;
    const int jc = blockIdx.y;
    const int chunk = (x + JSPLIT - 1) / JSPLIT;
    const int j0 = jc * chunk;
    int j1 = j0 + chunk; if (j1 > x) j1 = x;

    float4* wrow = ws + ((size_t)jc * B + b) * D4;
    const float4* p = hidden + ((size_t)b * S + start + j0) * D4;
    for (int d = tid; d < D4; d += 256) {
        float4 s = make_float4(0.f, 0.f, 0.f, 0.f);
        for (int j = 0; j < j1 - j0; ++j) {
            float4 h = p[(size_t)j * D4 + d];
            s.x += h.x; s.y += h.y; s.z += h.z; s.w += h.w;
        }
        wrow[d] = s;  // d_ws is poisoned: always write, even if chunk empty
    }
}

__global__ __launch_bounds__(256) void srs_reduce(
    const float4* __restrict__ ws,
    float4* __restrict__ out,
    int n)  // n = B*D4
{
    const int g = blockIdx.x * 256 + threadIdx.x;
    if (g >= n) return;
    float4 s = make_float4(0.f, 0.f, 0.f, 0.f);
    #pragma unroll
    for (int jc = 0; jc < JSPLIT; ++jc) {
        float4 h = ws[(size_t)jc * n + g];
        s.x += h.x; s.y += h.y; s.z += h.z; s.w += h.w;
    }
    out[g] = s;
}

extern "C" void kernel_launch(void* const* d_in, const int* in_sizes, int n_in,
                              void* d_out, int out_size, void* d_ws, size_t ws_size,
                              hipStream_t stream) {
    const float* hidden = (const float*)d_in[0];
    const int*   mask   = (const int*)d_in[1];
    const int*   xp     = (const int*)d_in[2];

    const long long nhid  = in_sizes[0];  // B*S*D
    const long long nmask = in_sizes[1];  // B*S
    const int D  = (int)(nhid / nmask);
    const int S  = (int)(nhid / (long long)out_size);  // (B*S*D)/(B*D)
    const int B  = out_size / D;
    const int D4 = D / 4;
    const int n  = B * D4;

    dim3 g1(B, JSPLIT);
    srs_partial<<<g1, 256, 0, stream>>>(
        (const float4*)hidden, mask, xp, (float4*)d_ws, B, S, D4);
    srs_reduce<<<(n + 255) / 256, 256, 0, stream>>>(
        (const float4*)d_ws, (float4*)d_out, n);
}